// Round 1
// baseline (351.561 us; speedup 1.0000x reference)
//
#include <hip/hip_runtime.h>
#include <stdint.h>

#define E 1024
#define S 2048
#define BATCH 2
#define NH 16
#define HD 64

typedef _Float16 f16;
typedef _Float16 f16x4 __attribute__((ext_vector_type(4)));
typedef _Float16 f16x8 __attribute__((ext_vector_type(8)));
typedef float f32x4 __attribute__((ext_vector_type(4)));

__device__ __forceinline__ void async16(const void* g, void* l) {
  __builtin_amdgcn_global_load_lds(
      (const __attribute__((address_space(1))) unsigned int*)g,
      (__attribute__((address_space(3))) unsigned int*)l, 16, 0, 0);
}

// ---------------- conversion kernels ----------------

// x (4096x1024 fp32) -> xh, xl (fp16 split)
__global__ __launch_bounds__(256) void cvt_x(const float* __restrict__ x,
                                             f16* __restrict__ xh,
                                             f16* __restrict__ xl) {
  int i = (blockIdx.x * 256 + threadIdx.x) * 4;
  float4 a = *(const float4*)(x + i);
  f16 h0 = (f16)a.x, h1 = (f16)a.y, h2 = (f16)a.z, h3 = (f16)a.w;
  f16x4 hv = {h0, h1, h2, h3};
  f16x4 lv = {(f16)(a.x - (float)h0), (f16)(a.y - (float)h1),
              (f16)(a.z - (float)h2), (f16)(a.w - (float)h3)};
  *(f16x4*)(xh + i) = hv;
  *(f16x4*)(xl + i) = lv;
}

// W (1024x1024 fp32, K-major rows) -> Wt (N x K, fp16). z in {0:q,1:k,2:v,3:o}.
// q,k also get a low-part (split).
__global__ __launch_bounds__(256) void cvt_w(const float* __restrict__ Wq,
                                             const float* __restrict__ Wk,
                                             const float* __restrict__ Wv,
                                             const float* __restrict__ Wo,
                                             f16* __restrict__ Wh,
                                             f16* __restrict__ Wl) {
  __shared__ float tile[32][33];
  const int z = blockIdx.z;
  const float* W = z == 0 ? Wq : z == 1 ? Wk : z == 2 ? Wv : Wo;
  const int tx = threadIdx.x, ty = threadIdx.y;  // 32 x 8
  const int x0 = blockIdx.x * 32, y0 = blockIdx.y * 32;
#pragma unroll
  for (int i = 0; i < 4; i++)
    tile[ty + i * 8][tx] = W[(size_t)(y0 + ty + i * 8) * E + x0 + tx];
  __syncthreads();
  f16* outh = Wh + (size_t)z * E * E;
  f16* outl = Wl + (size_t)z * E * E;  // only used for z<2
#pragma unroll
  for (int i = 0; i < 4; i++) {
    float v = tile[tx][ty + i * 8];
    size_t o = (size_t)(x0 + ty + i * 8) * E + (y0 + tx);  // [n][k]
    f16 hi = (f16)v;
    outh[o] = hi;
    if (z < 2) outl[o] = (f16)(v - (float)hi);
  }
}

// ---------------- GEMM mainloop (C = A * B^T, both K-major fp16) ----------------
// 128x128 tile, BK=32, 256 threads (4 waves), each wave 64x64 (4x4 MFMA tiles).
// LDS tiles XOR-chunk-swizzled: chunk_slot = chunk ^ ((row>>1)&3)  (4 chunks/row).

template <bool SPLIT2>
__device__ __forceinline__ void gemm_mainloop(
    const f16* __restrict__ Ah, const f16* __restrict__ Al,
    const f16* __restrict__ Bh, const f16* __restrict__ Bl, int m0, int n0,
    int K, f16* Ahs, f16* Als, f16* Bhs, f16* Bls, f32x4 acc[4][4]) {
  const int tid = threadIdx.x, lane = tid & 63, wid = tid >> 6;
  const int quad = lane >> 4, c16 = lane & 15;
  // staging: slot = inst*256+tid; row = slot>>2 (0..127), chunk_slot = tid&3
  const int rA = tid >> 2;
  const int cA = (tid & 3) ^ ((rA >> 1) & 3);  // same xor for row and row+64
  const size_t gA0 = (size_t)(m0 + rA) * K + cA * 8;
  const size_t gA1 = (size_t)(m0 + 64 + rA) * K + cA * 8;
  const size_t gB0 = (size_t)(n0 + rA) * K + cA * 8;
  const size_t gB1 = (size_t)(n0 + 64 + rA) * K + cA * 8;
  const int l0 = tid * 8, l1 = (256 + tid) * 8;
  int a_off[4], b_off[4];
#pragma unroll
  for (int i = 0; i < 4; i++) {
    int ra = (wid >> 1) * 64 + i * 16 + c16;
    a_off[i] = ra * 32 + ((quad ^ ((ra >> 1) & 3)) << 3);
    int rb = (wid & 1) * 64 + i * 16 + c16;
    b_off[i] = rb * 32 + ((quad ^ ((rb >> 1) & 3)) << 3);
  }
  for (int k0 = 0; k0 < K; k0 += 32) {
    __syncthreads();
    async16(Ah + gA0 + k0, Ahs + l0);
    async16(Ah + gA1 + k0, Ahs + l1);
    async16(Bh + gB0 + k0, Bhs + l0);
    async16(Bh + gB1 + k0, Bhs + l1);
    if constexpr (SPLIT2) {
      async16(Al + gA0 + k0, Als + l0);
      async16(Al + gA1 + k0, Als + l1);
      async16(Bl + gB0 + k0, Bls + l0);
      async16(Bl + gB1 + k0, Bls + l1);
    }
    __syncthreads();
    f16x8 ah[4], bh[4];
#pragma unroll
    for (int i = 0; i < 4; i++) {
      ah[i] = *(const f16x8*)(Ahs + a_off[i]);
      bh[i] = *(const f16x8*)(Bhs + b_off[i]);
    }
    if constexpr (SPLIT2) {
      f16x8 al[4], bl[4];
#pragma unroll
      for (int i = 0; i < 4; i++) {
        al[i] = *(const f16x8*)(Als + a_off[i]);
        bl[i] = *(const f16x8*)(Bls + b_off[i]);
      }
#pragma unroll
      for (int i = 0; i < 4; i++)
#pragma unroll
        for (int j = 0; j < 4; j++) {
          acc[i][j] = __builtin_amdgcn_mfma_f32_16x16x32_f16(ah[i], bh[j], acc[i][j], 0, 0, 0);
          acc[i][j] = __builtin_amdgcn_mfma_f32_16x16x32_f16(ah[i], bl[j], acc[i][j], 0, 0, 0);
          acc[i][j] = __builtin_amdgcn_mfma_f32_16x16x32_f16(al[i], bh[j], acc[i][j], 0, 0, 0);
        }
    } else {
#pragma unroll
      for (int i = 0; i < 4; i++)
#pragma unroll
        for (int j = 0; j < 4; j++)
          acc[i][j] = __builtin_amdgcn_mfma_f32_16x16x32_f16(ah[i], bh[j], acc[i][j], 0, 0, 0);
    }
  }
}

// ---------------- QKV projection ----------------
// z=0: Q (split out), z=1: K (split out), z=2: V (plain, transposed (B,H,D,S))
__global__ __launch_bounds__(256) void qkv_gemm(
    const f16* __restrict__ xh, const f16* __restrict__ xl,
    const f16* __restrict__ Wh, const f16* __restrict__ Wl,
    f16* __restrict__ Qh, f16* __restrict__ Ql, f16* __restrict__ Kh,
    f16* __restrict__ Kl, f16* __restrict__ Vt) {
  __shared__ __align__(16) f16 Ahs[4096], Als[4096], Bhs[4096], Bls[4096];
  const int z = blockIdx.z;
  const int m0 = blockIdx.y * 128, n0 = blockIdx.x * 128;
  const f16* Bth = Wh + (size_t)z * E * E;
  const f16* Btl = Wl + (size_t)z * E * E;
  f32x4 acc[4][4];
  const f32x4 zero4 = {0.f, 0.f, 0.f, 0.f};
#pragma unroll
  for (int i = 0; i < 4; i++)
#pragma unroll
    for (int j = 0; j < 4; j++) acc[i][j] = zero4;
  if (z < 2)
    gemm_mainloop<true>(xh, xl, Bth, Btl, m0, n0, E, Ahs, Als, Bhs, Bls, acc);
  else
    gemm_mainloop<false>(xh, nullptr, Bth, nullptr, m0, n0, E, Ahs, Als, Bhs, Bls, acc);
  const int lane = threadIdx.x & 63, wid = threadIdx.x >> 6;
  const int quad = lane >> 4, c16 = lane & 15;
#pragma unroll
  for (int i = 0; i < 4; i++)
#pragma unroll
    for (int j = 0; j < 4; j++)
#pragma unroll
      for (int r = 0; r < 4; r++) {
        int row = m0 + (wid >> 1) * 64 + i * 16 + quad * 4 + r;  // token
        int col = n0 + (wid & 1) * 64 + j * 16 + c16;            // embed idx
        int b = row >> 11, s = row & (S - 1);
        int h = col >> 6, d = col & 63;
        float v = acc[i][j][r];
        if (z == 2) {
          Vt[((size_t)(b * NH + h) * HD + d) * S + s] = (f16)v;
        } else {
          size_t idx = (((size_t)(b * NH + h) * S + s) << 6) + d;
          f16 hi = (f16)v;
          f16 lo = (f16)(v - (float)hi);
          if (z == 0) { Qh[idx] = hi; Ql[idx] = lo; }
          else        { Kh[idx] = hi; Kl[idx] = lo; }
        }
      }
}

// ---------------- flash attention ----------------
// block: 64 q-rows of one (b,h); 4 waves, wave w owns q-rows [16w,16w+16).
// K-tiles of 64; online softmax in exp2 domain; 3-pass split QK^T; fp16 P,V.
__global__ __launch_bounds__(256) void flash(
    const f16* __restrict__ Qh, const f16* __restrict__ Ql,
    const f16* __restrict__ Kh, const f16* __restrict__ Kl,
    const f16* __restrict__ Vt, f16* __restrict__ Ao) {
  __shared__ __align__(16) f16 Qhs[64 * 64], Qls[64 * 64];
  __shared__ __align__(16) f16 Khs[64 * 64], Kls[64 * 64];
  __shared__ __align__(16) f16 Vs[64 * 64], Ps[64 * 64];
  const int tid = threadIdx.x, lane = tid & 63, wid = tid >> 6;
  const int quad = lane >> 4, c16 = lane & 15;
  const int qt = 31 - blockIdx.x;  // heavy tiles first
  const int bh = blockIdx.y;
  const int q0 = qt * 64;
  const size_t bhoff = (size_t)bh * S * HD;
  {  // stage Q (hi+lo), 64x64, 8 chunks/row, swizzle chunk ^= row&7
    int s0 = tid, s1 = 256 + tid;
    int r0 = s0 >> 3, c0 = (s0 & 7) ^ (r0 & 7);
    int r1 = s1 >> 3, c1 = (s1 & 7) ^ (r1 & 7);
    async16(Qh + bhoff + (size_t)(q0 + r0) * HD + c0 * 8, Qhs + s0 * 8);
    async16(Qh + bhoff + (size_t)(q0 + r1) * HD + c1 * 8, Qhs + s1 * 8);
    async16(Ql + bhoff + (size_t)(q0 + r0) * HD + c0 * 8, Qls + s0 * 8);
    async16(Ql + bhoff + (size_t)(q0 + r1) * HD + c1 * 8, Qls + s1 * 8);
  }
  float mrow[4], lrow[4];
  f32x4 oacc[4];
  const f32x4 zero4 = {0.f, 0.f, 0.f, 0.f};
#pragma unroll
  for (int r = 0; r < 4; r++) { mrow[r] = -3.0e38f; lrow[r] = 0.f; oacc[r] = zero4; }
  const int wq = wid * 16;
  const int sw0 = ((quad) ^ (c16 & 7)) << 3;
  const int sw1 = ((4 + quad) ^ (c16 & 7)) << 3;
  const int niter = qt + 1;
  for (int it = 0; it < niter; ++it) {
    const int k0 = it * 64;
    __syncthreads();
    {  // stage Kh, Kl, V^T tiles
      int s0 = tid, s1 = 256 + tid;
      int r0 = s0 >> 3, c0 = (s0 & 7) ^ (r0 & 7);
      int r1 = s1 >> 3, c1 = (s1 & 7) ^ (r1 & 7);
      async16(Kh + bhoff + (size_t)(k0 + r0) * HD + c0 * 8, Khs + s0 * 8);
      async16(Kh + bhoff + (size_t)(k0 + r1) * HD + c1 * 8, Khs + s1 * 8);
      async16(Kl + bhoff + (size_t)(k0 + r0) * HD + c0 * 8, Kls + s0 * 8);
      async16(Kl + bhoff + (size_t)(k0 + r1) * HD + c1 * 8, Kls + s1 * 8);
      async16(Vt + bhoff + (size_t)r0 * S + k0 + c0 * 8, Vs + s0 * 8);
      async16(Vt + bhoff + (size_t)r1 * S + k0 + c1 * 8, Vs + s1 * 8);
    }
    __syncthreads();
    f32x4 sreg[4];
#pragma unroll
    for (int t = 0; t < 4; t++) sreg[t] = zero4;
#pragma unroll
    for (int ks = 0; ks < 2; ks++) {
      int sw = ks ? sw1 : sw0;
      int aoff = (wq + c16) * 64 + sw;
      f16x8 aqh = *(const f16x8*)(Qhs + aoff);
      f16x8 aql = *(const f16x8*)(Qls + aoff);
#pragma unroll
      for (int tn = 0; tn < 4; tn++) {
        int boff = (tn * 16 + c16) * 64 + sw;
        f16x8 bkh = *(const f16x8*)(Khs + boff);
        f16x8 bkl = *(const f16x8*)(Kls + boff);
        sreg[tn] = __builtin_amdgcn_mfma_f32_16x16x32_f16(aqh, bkh, sreg[tn], 0, 0, 0);
        sreg[tn] = __builtin_amdgcn_mfma_f32_16x16x32_f16(aqh, bkl, sreg[tn], 0, 0, 0);
        sreg[tn] = __builtin_amdgcn_mfma_f32_16x16x32_f16(aql, bkh, sreg[tn], 0, 0, 0);
      }
    }
    // online softmax (exp2 domain); scale = 0.125 * log2(e)
    const float cf = 0.18033688011112042f;
    const bool maskit = (it == niter - 1);
    float rmax[4] = {-3e38f, -3e38f, -3e38f, -3e38f};
#pragma unroll
    for (int tn = 0; tn < 4; tn++) {
      int kidx = k0 + tn * 16 + c16;
#pragma unroll
      for (int r = 0; r < 4; r++) {
        float sv = sreg[tn][r] * cf;
        if (maskit && kidx > q0 + wq + quad * 4 + r) sv = -1e30f;
        sreg[tn][r] = sv;
        rmax[r] = fmaxf(rmax[r], sv);
      }
    }
#pragma unroll
    for (int r = 0; r < 4; r++) {
#pragma unroll
      for (int m = 1; m < 16; m <<= 1)
        rmax[r] = fmaxf(rmax[r], __shfl_xor(rmax[r], m, 64));
    }
    float alpha[4], rsum[4];
#pragma unroll
    for (int r = 0; r < 4; r++) {
      float mn = fmaxf(mrow[r], rmax[r]);
      alpha[r] = __builtin_amdgcn_exp2f(mrow[r] - mn);
      mrow[r] = mn;
      rsum[r] = 0.f;
    }
#pragma unroll
    for (int tn = 0; tn < 4; tn++)
#pragma unroll
      for (int r = 0; r < 4; r++) {
        float p = __builtin_amdgcn_exp2f(sreg[tn][r] - mrow[r]);
        sreg[tn][r] = p;
        rsum[r] += p;
      }
#pragma unroll
    for (int r = 0; r < 4; r++) {
#pragma unroll
      for (int m = 1; m < 16; m <<= 1) rsum[r] += __shfl_xor(rsum[r], m, 64);
      lrow[r] = lrow[r] * alpha[r] + rsum[r];
    }
#pragma unroll
    for (int dt = 0; dt < 4; dt++) {
#pragma unroll
      for (int r = 0; r < 4; r++) oacc[dt][r] *= alpha[r];
    }
    // P -> LDS (swizzled); wave writes/reads only its own 16 rows
#pragma unroll
    for (int tn = 0; tn < 4; tn++) {
      int col = tn * 16 + c16;
      int cb = col >> 3, cl = col & 7;
#pragma unroll
      for (int r = 0; r < 4; r++) {
        int row = wq + quad * 4 + r;
        Ps[row * 64 + ((cb ^ (row & 7)) << 3) + cl] = (f16)sreg[tn][r];
      }
    }
    // O += P * V
#pragma unroll
    for (int ks = 0; ks < 2; ks++) {
      int sw = ks ? sw1 : sw0;
      f16x8 ap = *(const f16x8*)(Ps + (wq + c16) * 64 + sw);
#pragma unroll
      for (int dt = 0; dt < 4; dt++) {
        f16x8 bv = *(const f16x8*)(Vs + (dt * 16 + c16) * 64 + sw);
        oacc[dt] = __builtin_amdgcn_mfma_f32_16x16x32_f16(ap, bv, oacc[dt], 0, 0, 0);
      }
    }
  }
  // epilogue: normalize, write Ao in (B,S,E)
  const int b = bh >> 4, h = bh & 15;
  float inv[4];
#pragma unroll
  for (int r = 0; r < 4; r++) inv[r] = 1.0f / lrow[r];
#pragma unroll
  for (int dt = 0; dt < 4; dt++)
#pragma unroll
    for (int r = 0; r < 4; r++) {
      int srow = q0 + wq + quad * 4 + r;
      int d = dt * 16 + c16;
      Ao[((size_t)(b * S + srow)) * E + h * HD + d] = (f16)(oacc[dt][r] * inv[r]);
    }
}

// ---------------- output projection ----------------
__global__ __launch_bounds__(256) void out_gemm(const f16* __restrict__ Ao,
                                                const f16* __restrict__ Wo,
                                                float* __restrict__ Cout) {
  __shared__ __align__(16) f16 Ahs[4096], Bhs[4096];
  const int m0 = blockIdx.y * 128, n0 = blockIdx.x * 128;
  f32x4 acc[4][4];
  const f32x4 zero4 = {0.f, 0.f, 0.f, 0.f};
#pragma unroll
  for (int i = 0; i < 4; i++)
#pragma unroll
    for (int j = 0; j < 4; j++) acc[i][j] = zero4;
  gemm_mainloop<false>(Ao, nullptr, Wo, nullptr, m0, n0, E, Ahs, nullptr, Bhs, nullptr, acc);
  const int lane = threadIdx.x & 63, wid = threadIdx.x >> 6;
  const int quad = lane >> 4, c16 = lane & 15;
#pragma unroll
  for (int i = 0; i < 4; i++)
#pragma unroll
    for (int j = 0; j < 4; j++)
#pragma unroll
      for (int r = 0; r < 4; r++) {
        int row = m0 + (wid >> 1) * 64 + i * 16 + quad * 4 + r;
        int col = n0 + (wid & 1) * 64 + j * 16 + c16;
        Cout[(size_t)row * E + col] = acc[i][j][r];
      }
}

extern "C" void kernel_launch(void* const* d_in, const int* in_sizes, int n_in,
                              void* d_out, int out_size, void* d_ws,
                              size_t ws_size, hipStream_t stream) {
  const float* x = (const float*)d_in[0];
  const float* Wq = (const float*)d_in[1];
  const float* Wk = (const float*)d_in[2];
  const float* Wv = (const float*)d_in[3];
  const float* Wo = (const float*)d_in[4];
  char* ws = (char*)d_ws;
  const size_t MB = (size_t)1 << 20;
  f16* xh = (f16*)(ws + 0 * MB);    // 8 MB  (4096x1024)
  f16* xl = (f16*)(ws + 8 * MB);    // 8 MB
  f16* Wh = (f16*)(ws + 16 * MB);   // 8 MB  (4 mats, N-major)
  f16* Wl = (f16*)(ws + 24 * MB);   // 4 MB  (2 mats)
  f16* Qh = (f16*)(ws + 28 * MB);   // 8 MB  (B,H,S,D)
  f16* Ql = (f16*)(ws + 36 * MB);   // 8 MB
  f16* Kh = (f16*)(ws + 44 * MB);   // 8 MB
  f16* Kl = (f16*)(ws + 52 * MB);   // 8 MB
  f16* Vt = (f16*)(ws + 60 * MB);   // 8 MB  (B,H,D,S)
  f16* Ao = (f16*)(ws + 68 * MB);   // 8 MB  (B,S,E)
  cvt_x<<<4096, 256, 0, stream>>>(x, xh, xl);
  cvt_w<<<dim3(32, 32, 4), dim3(32, 8), 0, stream>>>(Wq, Wk, Wv, Wo, Wh, Wl);
  qkv_gemm<<<dim3(8, 32, 3), 256, 0, stream>>>(xh, xl, Wh, Wl, Qh, Ql, Kh, Kl, Vt);
  flash<<<dim3(32, 32), 256, 0, stream>>>(Qh, Ql, Kh, Kl, Vt, Ao);
  out_gemm<<<dim3(8, 32), 256, 0, stream>>>(Ao, Wh + (size_t)3 * E * E, (float*)d_out);
}

// Round 3
// 265.792 us; speedup vs baseline: 1.3227x; 1.3227x over previous
//
#include <hip/hip_runtime.h>
#include <stdint.h>

#define E 1024
#define S 2048
#define NH 16
#define HD 64

typedef _Float16 f16;
typedef _Float16 f16x4 __attribute__((ext_vector_type(4)));
typedef _Float16 f16x8 __attribute__((ext_vector_type(8)));
typedef __fp16 hv4 __attribute__((ext_vector_type(4)));
typedef float f32x4 __attribute__((ext_vector_type(4)));

__device__ __forceinline__ void async16(const void* g, void* l) {
  __builtin_amdgcn_global_load_lds(
      (const __attribute__((address_space(1))) unsigned int*)g,
      (__attribute__((address_space(3))) unsigned int*)l, 16, 0, 0);
}

// ---------------- conversion kernels ----------------

__global__ __launch_bounds__(256) void cvt_x(const float* __restrict__ x,
                                             f16* __restrict__ xh,
                                             f16* __restrict__ xl) {
  int i = (blockIdx.x * 256 + threadIdx.x) * 4;
  float4 a = *(const float4*)(x + i);
  f16 h0 = (f16)a.x, h1 = (f16)a.y, h2 = (f16)a.z, h3 = (f16)a.w;
  f16x4 hv = {h0, h1, h2, h3};
  f16x4 lv = {(f16)(a.x - (float)h0), (f16)(a.y - (float)h1),
              (f16)(a.z - (float)h2), (f16)(a.w - (float)h3)};
  *(f16x4*)(xh + i) = hv;
  *(f16x4*)(xl + i) = lv;
}

__global__ __launch_bounds__(256) void cvt_w(const float* __restrict__ Wq,
                                             const float* __restrict__ Wk,
                                             const float* __restrict__ Wv,
                                             const float* __restrict__ Wo,
                                             f16* __restrict__ Wh,
                                             f16* __restrict__ Wl) {
  __shared__ float tile[32][33];
  const int z = blockIdx.z;
  const float* W = z == 0 ? Wq : z == 1 ? Wk : z == 2 ? Wv : Wo;
  const int tx = threadIdx.x, ty = threadIdx.y;  // 32 x 8
  const int x0 = blockIdx.x * 32, y0 = blockIdx.y * 32;
#pragma unroll
  for (int i = 0; i < 4; i++)
    tile[ty + i * 8][tx] = W[(size_t)(y0 + ty + i * 8) * E + x0 + tx];
  __syncthreads();
  f16* outh = Wh + (size_t)z * E * E;
  f16* outl = Wl + (size_t)z * E * E;
#pragma unroll
  for (int i = 0; i < 4; i++) {
    float v = tile[tx][ty + i * 8];
    size_t o = (size_t)(x0 + ty + i * 8) * E + (y0 + tx);  // [n][k]
    f16 hi = (f16)v;
    outh[o] = hi;
    if (z < 2) outl[o] = (f16)(v - (float)hi);
  }
}

// ---------------- GEMM mainloop (C = A * B^T, both K-major fp16) ----------------

template <bool SPLIT2>
__device__ __forceinline__ void gemm_mainloop(
    const f16* __restrict__ Ah, const f16* __restrict__ Al,
    const f16* __restrict__ Bh, const f16* __restrict__ Bl, int m0, int n0,
    int K, f16* Ahs, f16* Als, f16* Bhs, f16* Bls, f32x4 acc[4][4]) {
  const int tid = threadIdx.x, lane = tid & 63, wid = tid >> 6;
  const int quad = lane >> 4, c16 = lane & 15;
  const int rA = tid >> 2;
  const int cA = (tid & 3) ^ ((rA >> 1) & 3);
  const size_t gA0 = (size_t)(m0 + rA) * K + cA * 8;
  const size_t gA1 = (size_t)(m0 + 64 + rA) * K + cA * 8;
  const size_t gB0 = (size_t)(n0 + rA) * K + cA * 8;
  const size_t gB1 = (size_t)(n0 + 64 + rA) * K + cA * 8;
  const int l0 = tid * 8, l1 = (256 + tid) * 8;
  int a_off[4], b_off[4];
#pragma unroll
  for (int i = 0; i < 4; i++) {
    int ra = (wid >> 1) * 64 + i * 16 + c16;
    a_off[i] = ra * 32 + ((quad ^ ((ra >> 1) & 3)) << 3);
    int rb = (wid & 1) * 64 + i * 16 + c16;
    b_off[i] = rb * 32 + ((quad ^ ((rb >> 1) & 3)) << 3);
  }
  for (int k0 = 0; k0 < K; k0 += 32) {
    __syncthreads();
    async16(Ah + gA0 + k0, Ahs + l0);
    async16(Ah + gA1 + k0, Ahs + l1);
    async16(Bh + gB0 + k0, Bhs + l0);
    async16(Bh + gB1 + k0, Bhs + l1);
    if constexpr (SPLIT2) {
      async16(Al + gA0 + k0, Als + l0);
      async16(Al + gA1 + k0, Als + l1);
      async16(Bl + gB0 + k0, Bls + l0);
      async16(Bl + gB1 + k0, Bls + l1);
    }
    __syncthreads();
    f16x8 ah[4], bh[4];
#pragma unroll
    for (int i = 0; i < 4; i++) {
      ah[i] = *(const f16x8*)(Ahs + a_off[i]);
      bh[i] = *(const f16x8*)(Bhs + b_off[i]);
    }
    if constexpr (SPLIT2) {
      f16x8 al[4], bl[4];
#pragma unroll
      for (int i = 0; i < 4; i++) {
        al[i] = *(const f16x8*)(Als + a_off[i]);
        bl[i] = *(const f16x8*)(Bls + b_off[i]);
      }
#pragma unroll
      for (int i = 0; i < 4; i++)
#pragma unroll
        for (int j = 0; j < 4; j++) {
          acc[i][j] = __builtin_amdgcn_mfma_f32_16x16x32_f16(ah[i], bh[j], acc[i][j], 0, 0, 0);
          acc[i][j] = __builtin_amdgcn_mfma_f32_16x16x32_f16(ah[i], bl[j], acc[i][j], 0, 0, 0);
          acc[i][j] = __builtin_amdgcn_mfma_f32_16x16x32_f16(al[i], bh[j], acc[i][j], 0, 0, 0);
        }
    } else {
#pragma unroll
      for (int i = 0; i < 4; i++)
#pragma unroll
        for (int j = 0; j < 4; j++)
          acc[i][j] = __builtin_amdgcn_mfma_f32_16x16x32_f16(ah[i], bh[j], acc[i][j], 0, 0, 0);
    }
  }
}

// ---------------- QKV projection ----------------
__global__ __launch_bounds__(256) void qkv_gemm(
    const f16* __restrict__ xh, const f16* __restrict__ xl,
    const f16* __restrict__ Wh, const f16* __restrict__ Wl,
    f16* __restrict__ Qh, f16* __restrict__ Ql, f16* __restrict__ Kh,
    f16* __restrict__ Kl, f16* __restrict__ Vt) {
  __shared__ __align__(16) char smem_raw[36864];
  f16* Ahs = (f16*)smem_raw;
  f16* Als = Ahs + 4096;
  f16* Bhs = Ahs + 8192;
  f16* Bls = Ahs + 12288;
  const int z = blockIdx.z;
  const int m0 = blockIdx.y * 128, n0 = blockIdx.x * 128;
  const f16* Bth = Wh + (size_t)z * E * E;
  const f16* Btl = Wl + (size_t)z * E * E;
  f32x4 acc[4][4];
  const f32x4 zero4 = {0.f, 0.f, 0.f, 0.f};
#pragma unroll
  for (int i = 0; i < 4; i++)
#pragma unroll
    for (int j = 0; j < 4; j++) acc[i][j] = zero4;
  if (z < 2)
    gemm_mainloop<true>(xh, xl, Bth, Btl, m0, n0, E, Ahs, Als, Bhs, Bls, acc);
  else
    gemm_mainloop<false>(xh, nullptr, Bth, nullptr, m0, n0, E, Ahs, Als, Bhs, Bls, acc);
  const int tid = threadIdx.x, lane = tid & 63, wid = tid >> 6;
  const int quad = lane >> 4, c16 = lane & 15;
  if (z == 2) {
    // transpose wave's 64x64 tile through LDS, store Vt (B,H,D,S) coalesced
    __syncthreads();
    f16* vbuf = (f16*)smem_raw + (size_t)wid * 4608;  // 64 rows x 72 stride
#pragma unroll
    for (int i = 0; i < 4; i++)
#pragma unroll
      for (int j = 0; j < 4; j++)
#pragma unroll
        for (int r = 0; r < 4; r++) {
          int sl = i * 16 + quad * 4 + r;
          int dl = j * 16 + c16;
          vbuf[dl * 72 + sl] = (f16)acc[i][j][r];
        }
#pragma unroll
    for (int i2 = 0; i2 < 8; i2++) {
      int dl = i2 * 8 + (lane >> 3);
      int ck = lane & 7;
      f16x8 v8 = *(const f16x8*)(vbuf + dl * 72 + ck * 8);
      int dg = n0 + (wid & 1) * 64 + dl;
      int sg = m0 + (wid >> 1) * 64 + ck * 8;
      int b = sg >> 11, s = sg & (S - 1);
      int h = dg >> 6, d = dg & 63;
      *(f16x8*)(Vt + (((size_t)(b * NH + h) * HD + d) << 11) + s) = v8;
    }
  } else {
#pragma unroll
    for (int i = 0; i < 4; i++)
#pragma unroll
      for (int j = 0; j < 4; j++)
#pragma unroll
        for (int r = 0; r < 4; r++) {
          int row = m0 + (wid >> 1) * 64 + i * 16 + quad * 4 + r;  // token
          int col = n0 + (wid & 1) * 64 + j * 16 + c16;            // embed idx
          int b = row >> 11, s = row & (S - 1);
          int h = col >> 6, d = col & 63;
          float v = acc[i][j][r];
          size_t idx = (((size_t)(b * NH + h) * S + s) << 6) + d;
          f16 hi = (f16)v;
          f16 lo = (f16)(v - (float)hi);
          if (z == 0) { Qh[idx] = hi; Ql[idx] = lo; }
          else        { Kh[idx] = hi; Kl[idx] = lo; }
        }
  }
}

// ---------------- flash attention (S^T orientation) ----------------
// block: 128 q-rows of one (b,h); wave w owns q cols [32w, 32w+32) (2 subtiles).
// S^T = K·Q^T via 16x16x32; P^T feeds PV (O^T = V^T·P^T) via 16x16x16 directly
// from C-registers. K/V LDS double-buffered; Q in registers.
__global__ __launch_bounds__(256, 3) void flash(
    const f16* __restrict__ Qh, const f16* __restrict__ Ql,
    const f16* __restrict__ Kh, const f16* __restrict__ Kl,
    const f16* __restrict__ Vt, f16* __restrict__ Ao) {
  __shared__ __align__(16) f16 Khs[2][4096], Kls[2][4096], Vs[2][4096];
  const int tid = threadIdx.x, lane = tid & 63, wid = tid >> 6;
  const int quad = lane >> 4, c16 = lane & 15;
  // XCD swizzle: group same-bh blocks on one XCD, heavy q-tiles first
  const int flat = blockIdx.y * 16 + blockIdx.x;
  const int xcd = flat & 7, slot = flat >> 3;
  const int bh = xcd * 4 + (slot >> 4);
  const int qtile = 15 - (slot & 15);
  const int q0 = qtile * 128;
  const size_t bhoff = (size_t)bh * S * HD;
  const int qbase = wid * 32;
  // Q fragments in registers (B-operand layout: n=c16 -> q, k=quad*8+j -> d)
  f16x8 qf_h[2][2], qf_l[2][2];
#pragma unroll
  for (int qt = 0; qt < 2; qt++)
#pragma unroll
    for (int ks = 0; ks < 2; ks++) {
      int q = q0 + qbase + qt * 16 + c16;
      size_t off = bhoff + (size_t)q * HD + ks * 32 + quad * 8;
      qf_h[qt][ks] = *(const f16x8*)(Qh + off);
      qf_l[qt][ks] = *(const f16x8*)(Ql + off);
    }
  const int niter = 2 * qtile + 2;
  // staging helper
  const int s0 = tid, s1 = 256 + tid;
  const int r0 = s0 >> 3, cc0 = ((s0 & 7) ^ (r0 & 7)) * 8;
  const int r1 = s1 >> 3, cc1 = ((s1 & 7) ^ (r1 & 7)) * 8;
  auto stage = [&](int it, int b) {
    const size_t kb = bhoff + (size_t)(it * 64) * HD;
    async16(Kh + kb + r0 * HD + cc0, &Khs[b][s0 * 8]);
    async16(Kh + kb + r1 * HD + cc1, &Khs[b][s1 * 8]);
    async16(Kl + kb + r0 * HD + cc0, &Kls[b][s0 * 8]);
    async16(Kl + kb + r1 * HD + cc1, &Kls[b][s1 * 8]);
    const size_t vb = bhoff + (size_t)(it * 64);
    async16(Vt + vb + (size_t)r0 * S + cc0, &Vs[b][s0 * 8]);
    async16(Vt + vb + (size_t)r1 * S + cc1, &Vs[b][s1 * 8]);
  };
  stage(0, 0);
  float mrow[2] = {-3.0e38f, -3.0e38f}, lsum[2] = {0.f, 0.f};
  f32x4 oacc[4][2];  // O^T: [d-tile][q-subtile]; row=quad*4+r -> d, col=c16 -> q
  const f32x4 zero4 = {0.f, 0.f, 0.f, 0.f};
#pragma unroll
  for (int dt = 0; dt < 4; dt++)
#pragma unroll
    for (int qt = 0; qt < 2; qt++) oacc[dt][qt] = zero4;
  const int qrow0 = q0 + qbase + c16;
  const float cf = 0.18033688011112042f;  // 0.125 * log2(e)
  for (int it = 0; it < niter; ++it) {
    const int cur = it & 1;
    __syncthreads();  // drains prefetch of buf[cur]
    if (it + 1 < niter) stage(it + 1, cur ^ 1);
    const int k0 = it * 64;
    // --- S^T = K . Q^T ---
    f32x4 st[2][4];
#pragma unroll
    for (int qt = 0; qt < 2; qt++)
#pragma unroll
      for (int kt = 0; kt < 4; kt++) st[qt][kt] = zero4;
#pragma unroll
    for (int kt = 0; kt < 4; kt++) {
      int rowk = (kt * 16 + c16) * 64;
      int sx = c16 & 7;
      f16x8 kh0 = *(const f16x8*)&Khs[cur][rowk + ((quad ^ sx) << 3)];
      f16x8 kh1 = *(const f16x8*)&Khs[cur][rowk + (((4 + quad) ^ sx) << 3)];
      f16x8 kl0 = *(const f16x8*)&Kls[cur][rowk + ((quad ^ sx) << 3)];
      f16x8 kl1 = *(const f16x8*)&Kls[cur][rowk + (((4 + quad) ^ sx) << 3)];
#pragma unroll
      for (int qt = 0; qt < 2; qt++) {
        st[qt][kt] = __builtin_amdgcn_mfma_f32_16x16x32_f16(kh0, qf_h[qt][0], st[qt][kt], 0, 0, 0);
        st[qt][kt] = __builtin_amdgcn_mfma_f32_16x16x32_f16(kh1, qf_h[qt][1], st[qt][kt], 0, 0, 0);
        st[qt][kt] = __builtin_amdgcn_mfma_f32_16x16x32_f16(kh0, qf_l[qt][0], st[qt][kt], 0, 0, 0);
        st[qt][kt] = __builtin_amdgcn_mfma_f32_16x16x32_f16(kh1, qf_l[qt][1], st[qt][kt], 0, 0, 0);
        st[qt][kt] = __builtin_amdgcn_mfma_f32_16x16x32_f16(kl0, qf_h[qt][0], st[qt][kt], 0, 0, 0);
        st[qt][kt] = __builtin_amdgcn_mfma_f32_16x16x32_f16(kl1, qf_h[qt][1], st[qt][kt], 0, 0, 0);
      }
    }
    // --- online softmax (raw logits; scale folded into exp2) ---
    const bool maskit = (it >= 2 * qtile);
    hv4 pb[2][4];
#pragma unroll
    for (int qt = 0; qt < 2; qt++) {
      const int qrow = qrow0 + qt * 16;
      if (maskit) {
#pragma unroll
        for (int kt = 0; kt < 4; kt++) {
          int kb = k0 + kt * 16 + quad * 4;
#pragma unroll
          for (int r = 0; r < 4; r++)
            if (kb + r > qrow) st[qt][kt][r] = -3.0e38f;
        }
      }
      float mx = -3.0e38f;
#pragma unroll
      for (int kt = 0; kt < 4; kt++) {
        float a = fmaxf(fmaxf(st[qt][kt][0], st[qt][kt][1]),
                        fmaxf(st[qt][kt][2], st[qt][kt][3]));
        mx = fmaxf(mx, a);
      }
      mx = fmaxf(mx, __shfl_xor(mx, 16, 64));
      mx = fmaxf(mx, __shfl_xor(mx, 32, 64));
      float mn = fmaxf(mrow[qt], mx);
      float alpha = __builtin_amdgcn_exp2f((mrow[qt] - mn) * cf);
      mrow[qt] = mn;
      float ls = lsum[qt] * alpha;
      float mncf = mn * cf;
#pragma unroll
      for (int kt = 0; kt < 4; kt++) {
        float p0 = __builtin_amdgcn_exp2f(st[qt][kt][0] * cf - mncf);
        float p1 = __builtin_amdgcn_exp2f(st[qt][kt][1] * cf - mncf);
        float p2 = __builtin_amdgcn_exp2f(st[qt][kt][2] * cf - mncf);
        float p3 = __builtin_amdgcn_exp2f(st[qt][kt][3] * cf - mncf);
        ls += (p0 + p1) + (p2 + p3);
        hv4 pv = {(__fp16)p0, (__fp16)p1, (__fp16)p2, (__fp16)p3};
        pb[qt][kt] = pv;
      }
      lsum[qt] = ls;
#pragma unroll
      for (int dt = 0; dt < 4; dt++) {
        oacc[dt][qt][0] *= alpha;
        oacc[dt][qt][1] *= alpha;
        oacc[dt][qt][2] *= alpha;
        oacc[dt][qt][3] *= alpha;
      }
    }
    // --- O^T += V^T . P^T  (16x16x16, P^T straight from registers) ---
#pragma unroll
    for (int kt = 0; kt < 4; kt++) {
#pragma unroll
      for (int dt = 0; dt < 4; dt++) {
        int rowd = dt * 16 + c16;
        int cidx = (kt * 2 + (quad >> 1)) ^ (rowd & 7);
        hv4 vf = *(const hv4*)&Vs[cur][rowd * 64 + (cidx << 3) + (quad & 1) * 4];
#pragma unroll
        for (int qt = 0; qt < 2; qt++)
          oacc[dt][qt] = __builtin_amdgcn_mfma_f32_16x16x16f16(vf, pb[qt][kt], oacc[dt][qt], 0, 0, 0);
      }
    }
  }
  // --- epilogue ---
  const int bb = bh >> 4, hh = bh & 15;
  float inv[2];
#pragma unroll
  for (int qt = 0; qt < 2; qt++) {
    float l = lsum[qt];
    l += __shfl_xor(l, 16, 64);
    l += __shfl_xor(l, 32, 64);
    inv[qt] = 1.0f / l;
  }
#pragma unroll
  for (int dt = 0; dt < 4; dt++)
#pragma unroll
    for (int qt = 0; qt < 2; qt++) {
      float iv = inv[qt];
      f16x4 ov = {(f16)(oacc[dt][qt][0] * iv), (f16)(oacc[dt][qt][1] * iv),
                  (f16)(oacc[dt][qt][2] * iv), (f16)(oacc[dt][qt][3] * iv)};
      int q = q0 + qbase + qt * 16 + c16;
      *(f16x4*)(Ao + ((size_t)(bb * S + q)) * E + hh * 64 + dt * 16 + quad * 4) = ov;
    }
}

// ---------------- output projection ----------------
__global__ __launch_bounds__(256) void out_gemm(const f16* __restrict__ Ao,
                                                const f16* __restrict__ Wo,
                                                float* __restrict__ Cout) {
  __shared__ __align__(16) f16 Ahs[4096], Bhs[4096];
  const int m0 = blockIdx.y * 128, n0 = blockIdx.x * 128;
  f32x4 acc[4][4];
  const f32x4 zero4 = {0.f, 0.f, 0.f, 0.f};
#pragma unroll
  for (int i = 0; i < 4; i++)
#pragma unroll
    for (int j = 0; j < 4; j++) acc[i][j] = zero4;
  gemm_mainloop<false>(Ao, nullptr, Wo, nullptr, m0, n0, E, Ahs, nullptr, Bhs, nullptr, acc);
  const int lane = threadIdx.x & 63, wid = threadIdx.x >> 6;
  const int quad = lane >> 4, c16 = lane & 15;
#pragma unroll
  for (int i = 0; i < 4; i++)
#pragma unroll
    for (int j = 0; j < 4; j++)
#pragma unroll
      for (int r = 0; r < 4; r++) {
        int row = m0 + (wid >> 1) * 64 + i * 16 + quad * 4 + r;
        int col = n0 + (wid & 1) * 64 + j * 16 + c16;
        Cout[(size_t)row * E + col] = acc[i][j][r];
      }
}

extern "C" void kernel_launch(void* const* d_in, const int* in_sizes, int n_in,
                              void* d_out, int out_size, void* d_ws,
                              size_t ws_size, hipStream_t stream) {
  const float* x = (const float*)d_in[0];
  const float* Wq = (const float*)d_in[1];
  const float* Wk = (const float*)d_in[2];
  const float* Wv = (const float*)d_in[3];
  const float* Wo = (const float*)d_in[4];
  char* ws = (char*)d_ws;
  const size_t MB = (size_t)1 << 20;
  f16* xh = (f16*)(ws + 0 * MB);
  f16* xl = (f16*)(ws + 8 * MB);
  f16* Wh = (f16*)(ws + 16 * MB);
  f16* Wl = (f16*)(ws + 24 * MB);
  f16* Qh = (f16*)(ws + 28 * MB);
  f16* Ql = (f16*)(ws + 36 * MB);
  f16* Kh = (f16*)(ws + 44 * MB);
  f16* Kl = (f16*)(ws + 52 * MB);
  f16* Vt = (f16*)(ws + 60 * MB);
  f16* Ao = (f16*)(ws + 68 * MB);
  cvt_x<<<4096, 256, 0, stream>>>(x, xh, xl);
  cvt_w<<<dim3(32, 32, 4), dim3(32, 8), 0, stream>>>(Wq, Wk, Wv, Wo, Wh, Wl);
  qkv_gemm<<<dim3(8, 32, 3), 256, 0, stream>>>(xh, xl, Wh, Wl, Qh, Ql, Kh, Kl, Vt);
  flash<<<dim3(16, 32), 256, 0, stream>>>(Qh, Ql, Kh, Kl, Vt, Ao);
  out_gemm<<<dim3(8, 32), 256, 0, stream>>>(Ao, Wh + (size_t)3 * E * E, (float*)d_out);
}